// Round 3
// baseline (118.893 us; speedup 1.0000x reference)
//
#include <hip/hip_runtime.h>
#include <math.h>

// RNTN over a complete binary tree, E=32 (EE=1024 floats per state matrix).
// Levels are computed oldest-first; leaves are fused into the level-1 kernel
// since each leaf is consumed by exactly one internal node.
// d_ws layout: states for internal nodes only: states[(node - L) * 1024].

#define EE 1024

__device__ __forceinline__ float4 relu4(float4 v) {
    v.x = fmaxf(v.x, 0.f); v.y = fmaxf(v.y, 0.f);
    v.z = fmaxf(v.z, 0.f); v.w = fmaxf(v.w, 0.f);
    return v;
}

// One block (256 threads) per internal node at this level.
// LEAFKIDS: children are leaves -> child state = relu(emb[words[child]]).
template<bool LEAFKIDS>
__global__ __launch_bounds__(256) void level_kernel(
    const int* __restrict__ words, const int* __restrict__ left,
    const int* __restrict__ right, const float* __restrict__ emb,
    const float* __restrict__ bias, float* __restrict__ states,
    int base, int Lleaves)
{
    const int node = base + blockIdx.x;
    const int t = threadIdx.x;
    __shared__ float sW[EE], sL[EE], sR[EE], sT[EE];

    const int li = left[node], ri = right[node];
    const float4* Wv = reinterpret_cast<const float4*>(emb + (size_t)words[node] * EE);
    const float4 *Lv, *Rv;
    if (LEAFKIDS) {
        Lv = reinterpret_cast<const float4*>(emb + (size_t)words[li] * EE);
        Rv = reinterpret_cast<const float4*>(emb + (size_t)words[ri] * EE);
    } else {
        Lv = reinterpret_cast<const float4*>(states + (size_t)(li - Lleaves) * EE);
        Rv = reinterpret_cast<const float4*>(states + (size_t)(ri - Lleaves) * EE);
    }
    float4 vw = Wv[t], vl = Lv[t], vr = Rv[t];
    if (LEAFKIDS) { vl = relu4(vl); vr = relu4(vr); }
    reinterpret_cast<float4*>(sW)[t] = vw;
    reinterpret_cast<float4*>(sL)[t] = vl;
    reinterpret_cast<float4*>(sR)[t] = vr;
    __syncthreads();

    // T = W @ R   (each thread: 4 of the 1024 outputs)
    #pragma unroll
    for (int p = 0; p < 4; ++p) {
        const int o = t + p * 256, r = o >> 5, c = o & 31;
        float acc = 0.f;
        #pragma unroll
        for (int k = 0; k < 32; ++k) acc = fmaf(sW[r * 32 + k], sR[k * 32 + c], acc);
        sT[o] = acc;  // distinct buffer: no hazard vs sW/sR reads
    }
    __syncthreads();

    // state = relu(L @ T + bias)
    #pragma unroll
    for (int p = 0; p < 4; ++p) {
        const int o = t + p * 256, r = o >> 5, c = o & 31;
        float acc = bias[o];
        #pragma unroll
        for (int k = 0; k < 32; ++k) acc = fmaf(sL[r * 32 + k], sT[k * 32 + c], acc);
        states[(size_t)(node - Lleaves) * EE + o] = fmaxf(acc, 0.f);
    }
}

// Single block handles the last 4 levels (8+4+2+1 nodes) + projection head.
__global__ __launch_bounds__(1024) void tail_kernel(
    const int* __restrict__ words, const int* __restrict__ left,
    const int* __restrict__ right, const float* __restrict__ emb,
    const float* __restrict__ bias, float* __restrict__ states,
    const float* __restrict__ W_proj, const float* __restrict__ b_proj,
    const int* __restrict__ label, float* __restrict__ out,
    int base0, int Lleaves)
{
    __shared__ float sT[8 * EE];   // 32 KB
    __shared__ float sLog[128];
    const int t = threadIdx.x;

    int base = base0;
    for (int cnt = 8; cnt >= 1; cnt >>= 1) {
        const int total = cnt << 10;
        for (int o = t; o < total; o += 1024) {
            const int n = o >> 10, e = o & 1023, r = e >> 5, c = e & 31;
            const int node = base + n;
            const float* W = emb + (size_t)words[node] * EE;
            const float* R = states + (size_t)(right[node] - Lleaves) * EE;
            float acc = 0.f;
            #pragma unroll
            for (int k = 0; k < 32; ++k) acc = fmaf(W[r * 32 + k], R[k * 32 + c], acc);
            sT[o] = acc;
        }
        __syncthreads();
        for (int o = t; o < total; o += 1024) {
            const int n = o >> 10, e = o & 1023, r = e >> 5, c = e & 31;
            const int node = base + n;
            const float* Ls = states + (size_t)(left[node] - Lleaves) * EE;
            float acc = bias[e];
            #pragma unroll
            for (int k = 0; k < 32; ++k)
                acc = fmaf(Ls[r * 32 + k], sT[(n << 10) + k * 32 + c], acc);
            states[(size_t)(node - Lleaves) * EE + e] = fmaxf(acc, 0.f);
        }
        __threadfence_block();
        __syncthreads();
        base += cnt;
    }

    // Head: logits = root @ W_proj^T + b_proj ; loss = -log_softmax[label]
    const float* root = states + (size_t)(base - 1 - Lleaves) * EE;
    {
        const int j = t >> 3, part = t & 7;   // 8 threads per logit
        const float* Wr = W_proj + (size_t)j * EE + part * 128;
        const float* rt = root + part * 128;
        float acc = 0.f;
        #pragma unroll
        for (int k = 0; k < 128; k += 4) {
            const float4 w4 = *reinterpret_cast<const float4*>(Wr + k);
            const float4 r4 = *reinterpret_cast<const float4*>(rt + k);
            acc = fmaf(w4.x, r4.x, acc);
            acc = fmaf(w4.y, r4.y, acc);
            acc = fmaf(w4.z, r4.z, acc);
            acc = fmaf(w4.w, r4.w, acc);
        }
        acc += __shfl_xor(acc, 1);
        acc += __shfl_xor(acc, 2);
        acc += __shfl_xor(acc, 4);
        if (part == 0) sLog[j] = acc + b_proj[j];
    }
    __syncthreads();

    if (t < 64) {  // wave 0: max/argmax (first-index tie-break), logsumexp
        const float v0 = sLog[t], v1 = sLog[t + 64];
        float m; int mi;
        if (v1 > v0) { m = v1; mi = t + 64; } else { m = v0; mi = t; }
        #pragma unroll
        for (int d = 1; d < 64; d <<= 1) {
            const float om = __shfl_xor(m, d);
            const int omi = __shfl_xor(mi, d);
            if (om > m || (om == m && omi < mi)) { m = om; mi = omi; }
        }
        float se = expf(v0 - m) + expf(v1 - m);
        #pragma unroll
        for (int d = 1; d < 64; d <<= 1) se += __shfl_xor(se, d);
        if (t == 0) {
            out[0] = (float)mi;                              // prediction
            out[1] = -(sLog[label[0]] - m - logf(se));       // loss
        }
    }
}

extern "C" void kernel_launch(void* const* d_in, const int* in_sizes, int n_in,
                              void* d_out, int out_size, void* d_ws, size_t ws_size,
                              hipStream_t stream) {
    (void)n_in; (void)out_size; (void)ws_size;
    const int*   words  = (const int*)  d_in[0];
    const int*   left   = (const int*)  d_in[1];
    const int*   right  = (const int*)  d_in[2];
    // d_in[3] = is_leaf (unused: leaves are exactly nodes [0, L))
    const float* emb    = (const float*)d_in[4];
    const float* bias   = (const float*)d_in[5];
    const float* W_proj = (const float*)d_in[6];
    const float* b_proj = (const float*)d_in[7];
    const int*   label  = (const int*)  d_in[8];
    float* out    = (float*)d_out;
    float* states = (float*)d_ws;   // (N - L) * 1024 floats = 8.4 MB

    const int N = in_sizes[0];      // 4095
    const int L = (N + 1) / 2;      // 2048

    int base = L;
    int cnt  = L >> 1;              // 1024: children are leaves (fused relu)
    level_kernel<true><<<cnt, 256, 0, stream>>>(words, left, right, emb, bias,
                                                states, base, L);
    base += cnt; cnt >>= 1;
    for (; cnt > 8; cnt >>= 1) {    // 512, 256, 128, 64, 32, 16
        level_kernel<false><<<cnt, 256, 0, stream>>>(words, left, right, emb, bias,
                                                     states, base, L);
        base += cnt;
    }
    // levels 8, 4, 2, 1 + head in one block
    tail_kernel<<<1, 1024, 0, stream>>>(words, left, right, emb, bias, states,
                                        W_proj, b_proj, label, out, base, L);
}